// Round 8
// baseline (88.344 us; speedup 1.0000x reference)
//
#include <hip/hip_runtime.h>
#include <hip/hip_bf16.h>

#define S1 2048
#define S2 2048
#define FEAT 768
#define NB 8
#define BK 64
#define NKT (FEAT / BK)          // 12 K-steps

typedef __attribute__((ext_vector_type(8))) short bf16x8;
typedef __attribute__((ext_vector_type(4))) float f32x4;
typedef __attribute__((ext_vector_type(4))) unsigned short us4;
typedef __attribute__((address_space(1))) const unsigned int gu32;
typedef __attribute__((address_space(3))) unsigned int lu32;

static __device__ __forceinline__ unsigned short f2bf(float x) {
    unsigned u = __builtin_bit_cast(unsigned, x);
    unsigned r = u + 0x7FFFu + ((u >> 16) & 1u);   // RNE
    return (unsigned short)(r >> 16);
}

// ---------------- prepass: A=bf16(m1*wc), B=bf16(m2), Q=m1@wq, D=m2@wd ----------------
__global__ __launch_bounds__(256) void conv_kernel(
    const float* __restrict__ m1, const float* __restrict__ m2,
    const float* __restrict__ wq, const float* __restrict__ wd,
    const float* __restrict__ wc,
    unsigned short* __restrict__ A, unsigned short* __restrict__ Bm,
    float* __restrict__ Q, float* __restrict__ D) {
    int wave = threadIdx.x >> 6;
    int lane = threadIdx.x & 63;
    int g = blockIdx.x * 4 + wave;               // 0 .. 2*NB*S1-1
    bool isA = (g < NB * S1);
    int row = isA ? g : g - NB * S1;
    const float* src = isA ? m1 : m2;
    const float* w   = isA ? wq : wd;
    unsigned short* dst = (isA ? A : Bm) + (size_t)row * FEAT;
    const float4* rp = (const float4*)(src + (size_t)row * FEAT);
    const float4* wp = (const float4*)w;
    const float4* cp = (const float4*)wc;
    float acc = 0.f;
#pragma unroll
    for (int i = 0; i < 3; ++i) {
        int idx = lane + 64 * i;
        float4 a = rp[idx];
        float4 b = wp[idx];
        acc += a.x * b.x + a.y * b.y + a.z * b.z + a.w * b.w;
        float4 c;
        if (isA) c = cp[idx]; else c = float4{1.f, 1.f, 1.f, 1.f};
        us4 v = { f2bf(a.x * c.x), f2bf(a.y * c.y),
                  f2bf(a.z * c.z), f2bf(a.w * c.w) };
        *(us4*)(dst + idx * 4) = v;
    }
#pragma unroll
    for (int s = 32; s; s >>= 1) acc += __shfl_xor(acc, s, 64);
    if (lane == 0) (isA ? Q : D)[row] = acc;
}

// ---------------- 128x128 tile, BK=64, single-buffer m97-structure GEMM ----------------
// 256 thr / 4 waves (2x2 of 64x64 out), 32 KB LDS, __launch_bounds__(256,4)
// -> 4 blocks/CU (16 waves/CU): inter-block overlap hides the per-K-tile
// stage->drain->compute stall (R4-R6 showed intra-block schedules don't).
// LDS rows 128 B; slot swizzle slot' = slot ^ (row&7): pre-swizzled global
// source col for global_load_lds (linear LDS dest, rule #21), XOR'd ds_read
// col. Proven conflict-free + correct in R2/R4/R6/R7.
__global__ __launch_bounds__(256, 4) void gemm128_kernel(
    const unsigned short* __restrict__ A, const unsigned short* __restrict__ Bm,
    const float* __restrict__ Q, const float* __restrict__ D,
    float* __restrict__ out) {

    __shared__ __align__(16) char sA[128 * 128];   // 16 KB
    __shared__ __align__(16) char sB[128 * 128];   // 16 KB

    // two-level swizzle: XCD owns batch (bid&7); within XCD walk 8x8 quadrants
    // so the resident tile window's A+B panels (3.1 MB) fit the 4 MB L2.
    const int bid = blockIdx.x;                    // 0..2047
    const int b   = bid & 7;                       // batch == XCD
    const int idx = bid >> 3;                      // 0..255 within batch
    const int qd  = idx >> 6;                      // quadrant 0..3
    const int w64 = idx & 63;
    const int tm  = ((qd >> 1) << 3) | (w64 >> 3);
    const int tn  = ((qd & 1) << 3) | (w64 & 7);

    const int tid  = threadIdx.x;
    const int lane = tid & 63;
    const int wave = tid >> 6;
    const int wm = wave >> 1, wn = wave & 1;       // 2x2 waves, 64x64 out each

    const char* Ab = (const char*)(A + ((size_t)b * S1 + (size_t)tm * 128) * FEAT);
    const char* Bb = (const char*)(Bm + ((size_t)b * S2 + (size_t)tn * 128) * FEAT);

    const int srow = lane >> 3;                            // 0..7
    const int scol = ((lane & 7) ^ (srow & 7)) * 16;       // pre-swizzled source col

    const int fr = lane & 15;                              // fragment row
    const int kg = lane >> 4;                              // K-group 0..3

    f32x4 acc[4][4];
#pragma unroll
    for (int m = 0; m < 4; ++m)
#pragma unroll
        for (int n = 0; n < 4; ++n) acc[m][n] = (f32x4)0.f;

#pragma unroll
    for (int kt = 0; kt < NKT; ++kt) {
        __syncthreads();                                   // prev frag reads done
#pragma unroll
        for (int i = 0; i < 4; ++i) {                      // stage A,B: 4 rows-of-8 each
            const int rb = wave * 32 + i * 8;
            __builtin_amdgcn_global_load_lds(
                (gu32*)(Ab + (size_t)(rb + srow) * (FEAT * 2) + kt * (BK * 2) + scol),
                (lu32*)(sA + rb * 128), 16, 0, 0);
            __builtin_amdgcn_global_load_lds(
                (gu32*)(Bb + (size_t)(rb + srow) * (FEAT * 2) + kt * (BK * 2) + scol),
                (lu32*)(sB + rb * 128), 16, 0, 0);
        }
        __syncthreads();                                   // drains vmcnt, tile ready

#pragma unroll
        for (int s = 0; s < 2; ++s) {                      // two K=32 sub-steps
            bf16x8 af[4], bfr[4];
#pragma unroll
            for (int m = 0; m < 4; ++m) {
                int r = wm * 64 + m * 16 + fr;
                int coff = (s * 64 + kg * 16) ^ ((r & 7) << 4);
                af[m] = *(const bf16x8*)(sA + r * 128 + coff);
            }
#pragma unroll
            for (int n = 0; n < 4; ++n) {
                int r = wn * 64 + n * 16 + fr;
                int coff = (s * 64 + kg * 16) ^ ((r & 7) << 4);
                bfr[n] = *(const bf16x8*)(sB + r * 128 + coff);
            }
#pragma unroll
            for (int m = 0; m < 4; ++m)
#pragma unroll
                for (int n = 0; n < 4; ++n)
                    acc[m][n] = __builtin_amdgcn_mfma_f32_16x16x32_bf16(
                        af[m], bfr[n], acc[m][n], 0, 0, 0);
        }
    }

    // ---------------- epilogue: + Q[j] + D[k], store fp32 ----------------
    const float* Qb = Q + b * S1 + tm * 128;
    const float* Db = D + b * S2 + tn * 128;
    float dv[4];
#pragma unroll
    for (int n = 0; n < 4; ++n) dv[n] = Db[wn * 64 + n * 16 + fr];

    const size_t outbase = ((size_t)b * S1 + (size_t)tm * 128) * S2 + (size_t)tn * 128;
#pragma unroll
    for (int m = 0; m < 4; ++m) {
#pragma unroll
        for (int i = 0; i < 4; ++i) {
            int rl = wm * 64 + m * 16 + kg * 4 + i;
            float qv = Qb[rl];
            float* orow = out + outbase + (size_t)rl * S2 + wn * 64;
#pragma unroll
            for (int n = 0; n < 4; ++n)
                orow[n * 16 + fr] = acc[m][n][i] + qv + dv[n];
        }
    }
}

// ================= fallback path (round-1, fp32 inputs) =================
__global__ __launch_bounds__(256) void qd_kernel(
    const float* __restrict__ m1, const float* __restrict__ m2,
    const float* __restrict__ wq, const float* __restrict__ wd,
    float* __restrict__ Q, float* __restrict__ D) {
    int wave = threadIdx.x >> 6;
    int lane = threadIdx.x & 63;
    int g = blockIdx.x * 4 + wave;
    const float* src; const float* w; float* dst; int row;
    if (g < NB * S1) { src = m1; w = wq; dst = Q; row = g; }
    else             { src = m2; w = wd; dst = D; row = g - NB * S1; }
    const float4* rp = (const float4*)(src + (size_t)row * FEAT);
    const float4* wp = (const float4*)w;
    float acc = 0.f;
#pragma unroll
    for (int i = 0; i < 3; ++i) {
        float4 a = rp[lane + 64 * i];
        float4 b = wp[lane + 64 * i];
        acc += a.x * b.x + a.y * b.y + a.z * b.z + a.w * b.w;
    }
#pragma unroll
    for (int s = 32; s; s >>= 1) acc += __shfl_xor(acc, s, 64);
    if (lane == 0) dst[row] = acc;
}

__global__ __launch_bounds__(256) void gemm_kernel(
    const float* __restrict__ m1, const float* __restrict__ m2,
    const float* __restrict__ wc,
    const float* __restrict__ Q, const float* __restrict__ D,
    float* __restrict__ out) {

    __shared__ __align__(16) char sA[128 * 64 * 2];
    __shared__ __align__(16) char sB[128 * 64 * 2];
    __shared__ float wcs[FEAT];

    const int tid = threadIdx.x;
    const int blk = blockIdx.x;
    const int b  = blk >> 8;
    const int t  = blk & 255;
    const int tm = t >> 4, tn = t & 15;

    for (int i = tid; i < FEAT; i += 256) wcs[i] = wc[i];

    const float* Abase = m1 + ((size_t)b * S1 + (size_t)tm * 128) * FEAT;
    const float* Bbase = m2 + ((size_t)b * S2 + (size_t)tn * 128) * FEAT;

    const int lane = tid & 63;
    const int wave = tid >> 6;
    const int wm = wave >> 1, wn = wave & 1;

    f32x4 acc[4][4];
#pragma unroll
    for (int m = 0; m < 4; ++m)
#pragma unroll
        for (int n = 0; n < 4; ++n) acc[m][n] = (f32x4)0.f;

    const int col4 = tid & 15;
    const int row0 = tid >> 4;

    __syncthreads();

    for (int ks = 0; ks < FEAT / 64; ++ks) {
        float4 wc4 = *(const float4*)&wcs[ks * 64 + col4 * 4];
        const float4* Ak = (const float4*)(Abase + ks * 64);
        const float4* Bk = (const float4*)(Bbase + ks * 64);

        __syncthreads();
#pragma unroll
        for (int i = 0; i < 8; ++i) {
            int r = row0 + 16 * i;
            float4 a = Ak[(size_t)r * (FEAT / 4) + col4];
            us4 av = { f2bf(a.x * wc4.x), f2bf(a.y * wc4.y),
                       f2bf(a.z * wc4.z), f2bf(a.w * wc4.w) };
            int off = r * 128 + ((col4 * 8) ^ ((r & 7) << 4));
            *(us4*)(sA + off) = av;
        }
#pragma unroll
        for (int i = 0; i < 8; ++i) {
            int r = row0 + 16 * i;
            float4 v = Bk[(size_t)r * (FEAT / 4) + col4];
            us4 bv = { f2bf(v.x), f2bf(v.y), f2bf(v.z), f2bf(v.w) };
            int off = r * 128 + ((col4 * 8) ^ ((r & 7) << 4));
            *(us4*)(sB + off) = bv;
        }
        __syncthreads();

#pragma unroll
        for (int s = 0; s < 2; ++s) {
            bf16x8 af[4], bfr[4];
#pragma unroll
            for (int m = 0; m < 4; ++m) {
                int r = wm * 64 + m * 16 + (lane & 15);
                int coff = (s * 64 + (lane >> 4) * 16) ^ ((r & 7) << 4);
                af[m] = *(const bf16x8*)(sA + r * 128 + coff);
            }
#pragma unroll
            for (int n = 0; n < 4; ++n) {
                int r = wn * 64 + n * 16 + (lane & 15);
                int coff = (s * 64 + (lane >> 4) * 16) ^ ((r & 7) << 4);
                bfr[n] = *(const bf16x8*)(sB + r * 128 + coff);
            }
#pragma unroll
            for (int m = 0; m < 4; ++m)
#pragma unroll
                for (int n = 0; n < 4; ++n)
                    acc[m][n] = __builtin_amdgcn_mfma_f32_16x16x32_bf16(
                        af[m], bfr[n], acc[m][n], 0, 0, 0);
        }
    }

    const float* Qb = Q + b * S1 + tm * 128;
    const float* Db = D + b * S2 + tn * 128;
    float dv[4];
#pragma unroll
    for (int n = 0; n < 4; ++n) dv[n] = Db[wn * 64 + n * 16 + (lane & 15)];

    const size_t outbase = ((size_t)b * S1 + (size_t)tm * 128) * S2 + (size_t)tn * 128;
#pragma unroll
    for (int m = 0; m < 4; ++m) {
#pragma unroll
        for (int i = 0; i < 4; ++i) {
            int rl = wm * 64 + m * 16 + (lane >> 4) * 4 + i;
            float qv = Qb[rl];
            float* orow = out + outbase + (size_t)rl * S2 + wn * 64;
#pragma unroll
            for (int n = 0; n < 4; ++n) {
                int cl = n * 16 + (lane & 15);
                orow[cl] = acc[m][n][i] + qv + dv[n];
            }
        }
    }
}

extern "C" void kernel_launch(void* const* d_in, const int* in_sizes, int n_in,
                              void* d_out, int out_size, void* d_ws, size_t ws_size,
                              hipStream_t stream) {
    const float* m1 = (const float*)d_in[0];
    const float* m2 = (const float*)d_in[1];
    const float* wq = (const float*)d_in[2];
    const float* wd = (const float*)d_in[3];
    const float* wc = (const float*)d_in[4];
    float* out = (float*)d_out;

    const size_t elems = (size_t)NB * S1 * FEAT;
    const size_t need = 2 * elems * sizeof(unsigned short)
                      + (size_t)(NB * S1 + NB * S2) * sizeof(float);

    if (ws_size >= need) {
        unsigned short* Abuf = (unsigned short*)d_ws;
        unsigned short* Bbuf = Abuf + elems;
        float* Q  = (float*)(Bbuf + elems);
        float* Dv = Q + NB * S1;
        conv_kernel<<<(NB * S1 + NB * S2) / 4, 256, 0, stream>>>(
            m1, m2, wq, wd, wc, Abuf, Bbuf, Q, Dv);
        gemm128_kernel<<<NB * 16 * 16, 256, 0, stream>>>(Abuf, Bbuf, Q, Dv, out);
    } else {
        float* Q  = (float*)d_ws;
        float* Dv = Q + NB * S1;
        qd_kernel<<<(2 * NB * S1) / 4, 256, 0, stream>>>(m1, m2, wq, wd, Q, Dv);
        gemm_kernel<<<NB * 256, 256, 0, stream>>>(m1, m2, wc, Q, Dv, out);
    }
}

// Round 9
// 86.510 us; speedup vs baseline: 1.0212x; 1.0212x over previous
//
#include <hip/hip_runtime.h>
#include <hip/hip_bf16.h>

#define S1 2048
#define S2 2048
#define FEAT 768
#define NB 8
#define BK 64
#define NKT (FEAT / BK)          // 12 K-steps

typedef __attribute__((ext_vector_type(8))) short bf16x8;
typedef __attribute__((ext_vector_type(4))) float f32x4;
typedef __attribute__((ext_vector_type(4))) unsigned short us4;
typedef __attribute__((address_space(1))) const unsigned int gu32;
typedef __attribute__((address_space(3))) unsigned int lu32;

static __device__ __forceinline__ unsigned short f2bf(float x) {
    unsigned u = __builtin_bit_cast(unsigned, x);
    unsigned r = u + 0x7FFFu + ((u >> 16) & 1u);   // RNE
    return (unsigned short)(r >> 16);
}

// ---------------- prepass: A=bf16(m1*wc), B=bf16(m2), Q=m1@wq, D=m2@wd ----------------
__global__ __launch_bounds__(256) void conv_kernel(
    const float* __restrict__ m1, const float* __restrict__ m2,
    const float* __restrict__ wq, const float* __restrict__ wd,
    const float* __restrict__ wc,
    unsigned short* __restrict__ A, unsigned short* __restrict__ Bm,
    float* __restrict__ Q, float* __restrict__ D) {
    int wave = threadIdx.x >> 6;
    int lane = threadIdx.x & 63;
    int g = blockIdx.x * 4 + wave;               // 0 .. 2*NB*S1-1
    bool isA = (g < NB * S1);
    int row = isA ? g : g - NB * S1;
    const float* src = isA ? m1 : m2;
    const float* w   = isA ? wq : wd;
    unsigned short* dst = (isA ? A : Bm) + (size_t)row * FEAT;
    const float4* rp = (const float4*)(src + (size_t)row * FEAT);
    const float4* wp = (const float4*)w;
    const float4* cp = (const float4*)wc;
    float acc = 0.f;
#pragma unroll
    for (int i = 0; i < 3; ++i) {
        int idx = lane + 64 * i;
        float4 a = rp[idx];
        float4 b = wp[idx];
        acc += a.x * b.x + a.y * b.y + a.z * b.z + a.w * b.w;
        float4 c;
        if (isA) c = cp[idx]; else c = float4{1.f, 1.f, 1.f, 1.f};
        us4 v = { f2bf(a.x * c.x), f2bf(a.y * c.y),
                  f2bf(a.z * c.z), f2bf(a.w * c.w) };
        *(us4*)(dst + idx * 4) = v;
    }
#pragma unroll
    for (int s = 32; s; s >>= 1) acc += __shfl_xor(acc, s, 64);
    if (lane == 0) (isA ? Q : D)[row] = acc;
}

// ---------------- 256x128 block tile, BK=64, 4 waves of 128x64 (8x4 acc) ----------------
// LDS-BW-per-MFMA lever: 8x4 acc -> (8+4)*2 frag reads per K64 = 384 B/instr
// read + 192 B/instr DMA-write = 576 B/instr (R8's 4x4 was 768) -> cap ~54%.
// Single 48 KB buffer, __launch_bounds__(256,2) -> 2 blocks/CU for latency
// overlap. Swizzle (slot' = slot ^ (row&7) on pre-swizzled global source,
// XOR'd ds_read col) proven conflict-free + correct in R2/R4/R6/R7/R8.
__global__ __launch_bounds__(256, 2) void gemm256x128_kernel(
    const unsigned short* __restrict__ A, const unsigned short* __restrict__ Bm,
    const float* __restrict__ Q, const float* __restrict__ D,
    float* __restrict__ out) {

    __shared__ __align__(16) char sA[256 * 128];   // 32 KB
    __shared__ __align__(16) char sB[128 * 128];   // 16 KB

    // XCD owns batch (bid&7); within XCD walk 2x4 quadrants of 4x4 tiles so
    // the resident window (4 A-panels + 4 B-panels = 2.3 MB) fits the 4MB L2.
    const int bid = blockIdx.x;                    // 0..1023
    const int b   = bid & 7;                       // batch == XCD
    const int idx = bid >> 3;                      // 0..127 (8 tm x 16 tn)
    const int qd  = idx >> 4;                      // quadrant 0..7 (2x4)
    const int w16 = idx & 15;
    const int tm  = ((qd >> 2) << 2) | (w16 >> 2); // 0..7
    const int tn  = ((qd & 3) << 2) | (w16 & 3);   // 0..15

    const int tid  = threadIdx.x;
    const int lane = tid & 63;
    const int wave = tid >> 6;
    const int wm = wave >> 1, wn = wave & 1;       // 2x2 waves: 128x64 out each

    const char* Ab = (const char*)(A + ((size_t)b * S1 + (size_t)tm * 256) * FEAT);
    const char* Bb = (const char*)(Bm + ((size_t)b * S2 + (size_t)tn * 128) * FEAT);

    const int srow = lane >> 3;                            // 0..7
    const int scol = ((lane & 7) ^ (srow & 7)) * 16;       // pre-swizzled source col

    const int fr = lane & 15;                              // fragment row
    const int kg = lane >> 4;                              // K-group 0..3

    f32x4 acc[8][4];
#pragma unroll
    for (int m = 0; m < 8; ++m)
#pragma unroll
        for (int n = 0; n < 4; ++n) acc[m][n] = (f32x4)0.f;

#pragma unroll
    for (int kt = 0; kt < NKT; ++kt) {
        __syncthreads();                                   // prev frag reads done
#pragma unroll
        for (int i = 0; i < 8; ++i) {                      // A: 64 rows per wave
            const int rb = wave * 64 + i * 8;
            __builtin_amdgcn_global_load_lds(
                (gu32*)(Ab + (size_t)(rb + srow) * (FEAT * 2) + kt * (BK * 2) + scol),
                (lu32*)(sA + rb * 128), 16, 0, 0);
        }
#pragma unroll
        for (int i = 0; i < 4; ++i) {                      // B: 32 rows per wave
            const int rb = wave * 32 + i * 8;
            __builtin_amdgcn_global_load_lds(
                (gu32*)(Bb + (size_t)(rb + srow) * (FEAT * 2) + kt * (BK * 2) + scol),
                (lu32*)(sB + rb * 128), 16, 0, 0);
        }
        __syncthreads();                                   // drains vmcnt, tile ready

#pragma unroll
        for (int s = 0; s < 2; ++s) {                      // two K=32 sub-steps
            bf16x8 af[8], bfr[4];
#pragma unroll
            for (int n = 0; n < 4; ++n) {
                int r = wn * 64 + n * 16 + fr;
                int coff = (s * 64 + kg * 16) ^ ((r & 7) << 4);
                bfr[n] = *(const bf16x8*)(sB + r * 128 + coff);
            }
#pragma unroll
            for (int m = 0; m < 8; ++m) {
                int r = wm * 128 + m * 16 + fr;
                int coff = (s * 64 + kg * 16) ^ ((r & 7) << 4);
                af[m] = *(const bf16x8*)(sA + r * 128 + coff);
            }
#pragma unroll
            for (int m = 0; m < 8; ++m)
#pragma unroll
                for (int n = 0; n < 4; ++n)
                    acc[m][n] = __builtin_amdgcn_mfma_f32_16x16x32_bf16(
                        af[m], bfr[n], acc[m][n], 0, 0, 0);
        }
    }

    // ---------------- epilogue: + Q[j] + D[k], store fp32 ----------------
    const float* Qb = Q + b * S1 + tm * 256;
    const float* Db = D + b * S2 + tn * 128;
    float dv[4];
#pragma unroll
    for (int n = 0; n < 4; ++n) dv[n] = Db[wn * 64 + n * 16 + fr];

    const size_t outbase = ((size_t)b * S1 + (size_t)tm * 256) * S2 + (size_t)tn * 128;
#pragma unroll
    for (int m = 0; m < 8; ++m) {
#pragma unroll
        for (int i = 0; i < 4; ++i) {
            int rl = wm * 128 + m * 16 + kg * 4 + i;
            float qv = Qb[rl];
            float* orow = out + outbase + (size_t)rl * S2 + wn * 64;
#pragma unroll
            for (int n = 0; n < 4; ++n)
                orow[n * 16 + fr] = acc[m][n][i] + qv + dv[n];
        }
    }
}

// ================= fallback path (round-1, fp32 inputs) =================
__global__ __launch_bounds__(256) void qd_kernel(
    const float* __restrict__ m1, const float* __restrict__ m2,
    const float* __restrict__ wq, const float* __restrict__ wd,
    float* __restrict__ Q, float* __restrict__ D) {
    int wave = threadIdx.x >> 6;
    int lane = threadIdx.x & 63;
    int g = blockIdx.x * 4 + wave;
    const float* src; const float* w; float* dst; int row;
    if (g < NB * S1) { src = m1; w = wq; dst = Q; row = g; }
    else             { src = m2; w = wd; dst = D; row = g - NB * S1; }
    const float4* rp = (const float4*)(src + (size_t)row * FEAT);
    const float4* wp = (const float4*)w;
    float acc = 0.f;
#pragma unroll
    for (int i = 0; i < 3; ++i) {
        float4 a = rp[lane + 64 * i];
        float4 b = wp[lane + 64 * i];
        acc += a.x * b.x + a.y * b.y + a.z * b.z + a.w * b.w;
    }
#pragma unroll
    for (int s = 32; s; s >>= 1) acc += __shfl_xor(acc, s, 64);
    if (lane == 0) dst[row] = acc;
}

__global__ __launch_bounds__(256) void gemm_kernel(
    const float* __restrict__ m1, const float* __restrict__ m2,
    const float* __restrict__ wc,
    const float* __restrict__ Q, const float* __restrict__ D,
    float* __restrict__ out) {

    __shared__ __align__(16) char sA[128 * 64 * 2];
    __shared__ __align__(16) char sB[128 * 64 * 2];
    __shared__ float wcs[FEAT];

    const int tid = threadIdx.x;
    const int blk = blockIdx.x;
    const int b  = blk >> 8;
    const int t  = blk & 255;
    const int tm = t >> 4, tn = t & 15;

    for (int i = tid; i < FEAT; i += 256) wcs[i] = wc[i];

    const float* Abase = m1 + ((size_t)b * S1 + (size_t)tm * 128) * FEAT;
    const float* Bbase = m2 + ((size_t)b * S2 + (size_t)tn * 128) * FEAT;

    const int lane = tid & 63;
    const int wave = tid >> 6;
    const int wm = wave >> 1, wn = wave & 1;

    f32x4 acc[4][4];
#pragma unroll
    for (int m = 0; m < 4; ++m)
#pragma unroll
        for (int n = 0; n < 4; ++n) acc[m][n] = (f32x4)0.f;

    const int col4 = tid & 15;
    const int row0 = tid >> 4;

    __syncthreads();

    for (int ks = 0; ks < FEAT / 64; ++ks) {
        float4 wc4 = *(const float4*)&wcs[ks * 64 + col4 * 4];
        const float4* Ak = (const float4*)(Abase + ks * 64);
        const float4* Bk = (const float4*)(Bbase + ks * 64);

        __syncthreads();
#pragma unroll
        for (int i = 0; i < 8; ++i) {
            int r = row0 + 16 * i;
            float4 a = Ak[(size_t)r * (FEAT / 4) + col4];
            us4 av = { f2bf(a.x * wc4.x), f2bf(a.y * wc4.y),
                       f2bf(a.z * wc4.z), f2bf(a.w * wc4.w) };
            int off = r * 128 + ((col4 * 8) ^ ((r & 7) << 4));
            *(us4*)(sA + off) = av;
        }
#pragma unroll
        for (int i = 0; i < 8; ++i) {
            int r = row0 + 16 * i;
            float4 v = Bk[(size_t)r * (FEAT / 4) + col4];
            us4 bv = { f2bf(v.x), f2bf(v.y), f2bf(v.z), f2bf(v.w) };
            int off = r * 128 + ((col4 * 8) ^ ((r & 7) << 4));
            *(us4*)(sB + off) = bv;
        }
        __syncthreads();

#pragma unroll
        for (int s = 0; s < 2; ++s) {
            bf16x8 af[4], bfr[4];
#pragma unroll
            for (int m = 0; m < 4; ++m) {
                int r = wm * 64 + m * 16 + (lane & 15);
                int coff = (s * 64 + (lane >> 4) * 16) ^ ((r & 7) << 4);
                af[m] = *(const bf16x8*)(sA + r * 128 + coff);
            }
#pragma unroll
            for (int n = 0; n < 4; ++n) {
                int r = wn * 64 + n * 16 + (lane & 15);
                int coff = (s * 64 + (lane >> 4) * 16) ^ ((r & 7) << 4);
                bfr[n] = *(const bf16x8*)(sB + r * 128 + coff);
            }
#pragma unroll
            for (int m = 0; m < 4; ++m)
#pragma unroll
                for (int n = 0; n < 4; ++n)
                    acc[m][n] = __builtin_amdgcn_mfma_f32_16x16x32_bf16(
                        af[m], bfr[n], acc[m][n], 0, 0, 0);
        }
    }

    const float* Qb = Q + b * S1 + tm * 128;
    const float* Db = D + b * S2 + tn * 128;
    float dv[4];
#pragma unroll
    for (int n = 0; n < 4; ++n) dv[n] = Db[wn * 64 + n * 16 + (lane & 15)];

    const size_t outbase = ((size_t)b * S1 + (size_t)tm * 128) * S2 + (size_t)tn * 128;
#pragma unroll
    for (int m = 0; m < 4; ++m) {
#pragma unroll
        for (int i = 0; i < 4; ++i) {
            int rl = wm * 64 + m * 16 + (lane >> 4) * 4 + i;
            float qv = Qb[rl];
            float* orow = out + outbase + (size_t)rl * S2 + wn * 64;
#pragma unroll
            for (int n = 0; n < 4; ++n) {
                int cl = n * 16 + (lane & 15);
                orow[cl] = acc[m][n][i] + qv + dv[n];
            }
        }
    }
}

extern "C" void kernel_launch(void* const* d_in, const int* in_sizes, int n_in,
                              void* d_out, int out_size, void* d_ws, size_t ws_size,
                              hipStream_t stream) {
    const float* m1 = (const float*)d_in[0];
    const float* m2 = (const float*)d_in[1];
    const float* wq = (const float*)d_in[2];
    const float* wd = (const float*)d_in[3];
    const float* wc = (const float*)d_in[4];
    float* out = (float*)d_out;

    const size_t elems = (size_t)NB * S1 * FEAT;
    const size_t need = 2 * elems * sizeof(unsigned short)
                      + (size_t)(NB * S1 + NB * S2) * sizeof(float);

    if (ws_size >= need) {
        unsigned short* Abuf = (unsigned short*)d_ws;
        unsigned short* Bbuf = Abuf + elems;
        float* Q  = (float*)(Bbuf + elems);
        float* Dv = Q + NB * S1;
        conv_kernel<<<(NB * S1 + NB * S2) / 4, 256, 0, stream>>>(
            m1, m2, wq, wd, wc, Abuf, Bbuf, Q, Dv);
        gemm256x128_kernel<<<NB * 128, 256, 0, stream>>>(Abuf, Bbuf, Q, Dv, out);
    } else {
        float* Q  = (float*)d_ws;
        float* Dv = Q + NB * S1;
        qd_kernel<<<(2 * NB * S1) / 4, 256, 0, stream>>>(m1, m2, wq, wd, Q, Dv);
        gemm_kernel<<<NB * 256, 256, 0, stream>>>(m1, m2, wc, Q, Dv, out);
    }
}